// Round 1
// baseline (783.409 us; speedup 1.0000x reference)
//
#include <hip/hip_runtime.h>
#include <math.h>

#define EPS 1e-5f

typedef __attribute__((ext_vector_type(4))) float floatx4;
typedef __attribute__((ext_vector_type(8))) short shortx8;

__device__ __forceinline__ unsigned short f2bf(float f){
  union { float f; unsigned u; } v; v.f = f;
  unsigned r = v.u + 0x7FFFu + ((v.u >> 16) & 1u);
  return (unsigned short)(r >> 16);
}
__device__ __forceinline__ float bf2f(unsigned short s){
  union { unsigned u; float f; } v; v.u = ((unsigned)s) << 16;
  return v.f;
}

// ---------------- K0: all weights -> bf16 transposed [n][k] ----------------
__global__ __launch_bounds__(256) void k_prep(
    const float* __restrict__ We, const float* __restrict__ Ws, const float* __restrict__ Wd,
    const float* __restrict__ Wqkv, const float* __restrict__ Wo, const float* __restrict__ W1,
    const float* __restrict__ W2, const float* __restrict__ Wb,
    unsigned short* __restrict__ WeT, unsigned short* __restrict__ WsT,
    unsigned short* __restrict__ WdT, unsigned short* __restrict__ WqkvT,
    unsigned short* __restrict__ WoT, unsigned short* __restrict__ W1T,
    unsigned short* __restrict__ W2T, unsigned short* __restrict__ WbT16)
{
  const int blk = blockIdx.x, tid = threadIdx.x;
  if (blk == 240){
#pragma unroll
    for (int hh=0; hh<8; hh++) WbT16[hh*256+tid] = f2bf(Wb[tid*8+hh]);
#pragma unroll
    for (int hh=8; hh<16; hh++) WbT16[hh*256+tid] = 0;
    return;
  }
  const float* src; unsigned short* dst; int K, N, t;
  if (blk < 16)      { src=We;   dst=WeT;   K=256;  N=256;  t=blk; }
  else if (blk < 32) { src=Ws;   dst=WsT;   K=256;  N=256;  t=blk-16; }
  else if (blk < 48) { src=Wd;   dst=WdT;   K=256;  N=256;  t=blk-32; }
  else if (blk < 96) { src=Wqkv; dst=WqkvT; K=256;  N=768;  t=blk-48; }
  else if (blk < 112){ src=Wo;   dst=WoT;   K=256;  N=256;  t=blk-96; }
  else if (blk < 176){ src=W1;   dst=W1T;   K=256;  N=1024; t=blk-112; }
  else               { src=W2;   dst=W2T;   K=1024; N=256;  t=blk-176; }
  const int tpr = N >> 6;
  const int k0 = (t / tpr) << 6, n0 = (t % tpr) << 6;
  __shared__ float tile[64][65];
#pragma unroll
  for (int s=0;s<16;s++){ int f=tid+(s<<8); int r=f>>6, c=f&63;
    tile[r][c] = src[(size_t)(k0+r)*N + n0 + c]; }
  __syncthreads();
#pragma unroll
  for (int s=0;s<16;s++){ int f=tid+(s<<8); int r=f>>6, c=f&63;
    dst[(size_t)(n0+r)*K + k0 + c] = f2bf(tile[c][r]); }
}

// ---------------- K1: fused front: S,T,Q,K,V (per 16-row block, per col-chunk) ----
__global__ __launch_bounds__(256) void k_front(
  const float* __restrict__ h, const float* __restrict__ g1, const float* __restrict__ b1l,
  const float* __restrict__ bs, const float* __restrict__ be, const float* __restrict__ bd,
  const float* __restrict__ bqkv,
  const unsigned short* __restrict__ WsT, const unsigned short* __restrict__ WdT,
  const unsigned short* __restrict__ WqkvT,
  float* __restrict__ S, float* __restrict__ T,
  unsigned short* __restrict__ Qb, unsigned short* __restrict__ Kb,
  unsigned short* __restrict__ VTb)
{
  __shared__ float hs[16][256];
  __shared__ __align__(16) unsigned short xa[16*264];
  __shared__ float red1[16][16], red2[16][16];
  __shared__ float rmean[16], rinv[16];
  const int tid = threadIdx.x;
  const int rb = blockIdx.x & 63;
  const int chunk = blockIdx.x >> 6;
  const int row0 = rb * 16;
  const int b = row0 >> 8;
  const int w = tid>>6, l = tid&63, lrow = l&15, quad = l>>4;

#pragma unroll
  for (int s=0;s<4;s++){
    int f = tid + s*256; int r = f>>6, c4 = f&63;
    float4 v = ((const float4*)(h + (size_t)row0*256))[f];
    *(float4*)(&hs[r][c4*4]) = v;
  }
  __syncthreads();
  {
    int row = tid>>4, l16 = tid&15;
    if (chunk >= 2){
      float sm=0.f, sq=0.f;
#pragma unroll
      for (int j=0;j<16;j++){ float v=hs[row][l16*16+j]; sm+=v; sq+=v*v; }
      red1[row][l16]=sm; red2[row][l16]=sq;
      __syncthreads();
      if (l16==0){
        float s0=0.f,q0=0.f;
#pragma unroll
        for(int k=0;k<16;k++){ s0+=red1[row][k]; q0+=red2[row][k]; }
        float m=s0*(1.f/256.f);
        rmean[row]=m; rinv[row]=rsqrtf(q0*(1.f/256.f)-m*m+EPS);
      }
      __syncthreads();
      float m=rmean[row], iv=rinv[row];
#pragma unroll
      for (int j=0;j<16;j++){ int col=l16*16+j;
        xa[row*264+col] = f2bf((hs[row][col]-m)*iv*g1[col] + b1l[col]); }
    } else {
#pragma unroll
      for (int j=0;j<16;j++){ int col=l16*16+j; xa[row*264+col] = f2bf(hs[row][col]); }
    }
  }
  __syncthreads();
  const unsigned short* Wt;
  if (chunk==0) Wt = WsT; else if (chunk==1) Wt = WdT;
  else Wt = WqkvT + (size_t)(chunk-2)*256*256;
  floatx4 a4[4];
#pragma unroll
  for (int t=0;t<4;t++) a4[t] = (floatx4){0.f,0.f,0.f,0.f};
  for (int c=0;c<8;c++){
    shortx8 af = *(const shortx8*)(xa + lrow*264 + c*32 + quad*8);
#pragma unroll
    for (int t=0;t<4;t++){
      int n = (w*4+t)*16 + lrow;
      shortx8 bf = *(const shortx8*)(Wt + (size_t)n*256 + c*32 + quad*8);
      a4[t] = __builtin_amdgcn_mfma_f32_16x16x32_bf16(af, bf, a4[t], 0, 0, 0);
    }
  }
#pragma unroll
  for (int t=0;t<4;t++){
    int ct = w*4+t;
#pragma unroll
    for (int reg=0;reg<4;reg++){
      int row = quad*4+reg, col = ct*16+lrow;
      float v = a4[t][reg];
      if (chunk==0) S[(size_t)(row0+row)*256+col] = v + bs[col] + be[col];
      else if (chunk==1) T[(size_t)(row0+row)*256+col] = v + bd[col];
      else if (chunk==2){ float q = v + bqkv[col]; int hh=col>>5, d=col&31;
        Qb[((size_t)(b*8+hh)*256 + (row0&255)+row)*32 + d] = f2bf(q); }
      else if (chunk==3){ float q = v + bqkv[256+col]; int hh=col>>5, d=col&31;
        Kb[((size_t)(b*8+hh)*256 + (row0&255)+row)*32 + d] = f2bf(q); }
      else { float q = v + bqkv[512+col]; int hh=col>>5, d=col&31;
        VTb[((size_t)(b*8+hh)*32 + d)*256 + (row0&255)+row] = f2bf(q); }
    }
  }
}

// ---------------- K2: e_new + fused bias — barrier-free, direct-from-global MFMA ----
// Operand swap: A = WeT fragment (out-dim = d), B = e fragment (out-dim = j).
// Thread (w, quad, lrow) owns output row j = j0 + w*16 + lrow, and for each of the
// 16 d-tiles holds d = t*16 + quad*4 + {0..3} (consecutive) -> vector epilogue.
// No As/Bs staging, no __syncthreads: WeT frags load straight from L2 (bf16),
// e frags load fp32 + in-register f2bf. Bias-MFMA A-frags read only En rows the
// SAME wave wrote (jloc = w*16+lrow), so compiler lgkmcnt ordering suffices.
__global__ __launch_bounds__(256, 3) void k_edge(
    const float* __restrict__ e, const unsigned short* __restrict__ WeT,
    const float* __restrict__ S, const float* __restrict__ T,
    const unsigned short* __restrict__ WbTg,
    float* __restrict__ eo, float* __restrict__ bias)
{
  __shared__ __align__(16) unsigned short En[64*264];  // 33792 B -> 4 blocks/CU by LDS

  const int tid = threadIdx.x;
  const int blk = blockIdx.x;
  const int jt = blk & 3;
  const int i  = (blk >> 2) & 255;
  const int b  = blk >> 10;
  const int j0 = jt * 64;
  const int w = tid >> 6, l = tid & 63;
  const int lrow = l & 15, quad = l >> 4;
  const int jloc = w*16 + lrow;            // this thread's j row (0..63)

  const float* eRow = e + ((size_t)((b*256 + i)*256 + j0 + jloc)) * 256 + quad*8;
  const float* Trow = T + ((size_t)(b*256 + j0 + jloc)) * 256;
  const float* Srow = S + ((size_t)(b*256 + i)) * 256;
  const unsigned short* wBase = WeT + lrow*256 + quad*8;

  floatx4 acc[16];
#pragma unroll
  for (int t = 0; t < 16; t++) acc[t] = (floatx4){0.f,0.f,0.f,0.f};

  // software-pipelined e-fragment (fp32 -> bf16 in registers)
  float4 e0 = *(const float4*)(eRow);
  float4 e1 = *(const float4*)(eRow + 4);

  for (int c = 0; c < 8; ++c){
    shortx8 ef;
    ef[0]=f2bf(e0.x); ef[1]=f2bf(e0.y); ef[2]=f2bf(e0.z); ef[3]=f2bf(e0.w);
    ef[4]=f2bf(e1.x); ef[5]=f2bf(e1.y); ef[6]=f2bf(e1.z); ef[7]=f2bf(e1.w);
    if (c < 7){
      e0 = *(const float4*)(eRow + (c+1)*32);
      e1 = *(const float4*)(eRow + (c+1)*32 + 4);
    }
    const unsigned short* wp = wBase + c*32;
#pragma unroll
    for (int t = 0; t < 16; ++t){
      shortx8 wf = *(const shortx8*)(wp + t*4096);   // WeT[(t*16+lrow)][c*32+quad*8..]
      acc[t] = __builtin_amdgcn_mfma_f32_16x16x32_bf16(wf, ef, acc[t], 0, 0, 0);
    }
  }

  // epilogue: v = acc + S[d] + T[j][d], relu; fp32 -> e_o directly (coalesced per row),
  // bf16 packed b64 -> En for the bias GEMM.
  float* eop = eo + ((size_t)((b*256 + i)*256 + j0 + jloc)) * 256;
#pragma unroll
  for (int t = 0; t < 16; ++t){
    const int d0 = t*16 + quad*4;
    float4 sv = *(const float4*)(Srow + d0);
    float4 tv = *(const float4*)(Trow + d0);
    float v0 = fmaxf(acc[t][0] + sv.x + tv.x, 0.f);
    float v1 = fmaxf(acc[t][1] + sv.y + tv.y, 0.f);
    float v2 = fmaxf(acc[t][2] + sv.z + tv.z, 0.f);
    float v3 = fmaxf(acc[t][3] + sv.w + tv.w, 0.f);
    float4 ov; ov.x = v0; ov.y = v1; ov.z = v2; ov.w = v3;
    *(float4*)(eop + d0) = ov;
    uint2 pk;
    pk.x = (unsigned int)f2bf(v0) | ((unsigned int)f2bf(v1) << 16);
    pk.y = (unsigned int)f2bf(v2) | ((unsigned int)f2bf(v3) << 16);
    *(uint2*)(En + jloc*264 + d0) = pk;
  }

  // fused bias: (64 j x 256 d) @ WbT -> [h][j]; A-frags are same-wave En rows,
  // B-frags straight from global (WbT16 is 8 KB, L2-hot).
  floatx4 accb = (floatx4){0.f,0.f,0.f,0.f};
#pragma unroll
  for (int c = 0; c < 8; c++){
    int k0 = c*32;
    shortx8 af = *(const shortx8*)(En + jloc*264 + k0 + quad*8);
    shortx8 bfrag = *(const shortx8*)(WbTg + lrow*256 + k0 + quad*8);
    accb = __builtin_amdgcn_mfma_f32_16x16x32_bf16(af, bfrag, accb, 0, 0, 0);
  }
  if (lrow < 8){
    float* bp = bias + ((size_t)((b*8 + lrow)*256 + i)) * 256;
    int jb = j0 + w*16 + quad*4;
#pragma unroll
    for (int r = 0; r < 4; r++) bp[jb + r] = accb[r];
  }
}

// ---------------- K3: attention, one block per (bh, 32-row i-chunk) ----------------
__global__ __launch_bounds__(256) void k_attn(
  const unsigned short* __restrict__ Qb, const unsigned short* __restrict__ Kb,
  const unsigned short* __restrict__ VTb, const float* __restrict__ bias,
  const float* __restrict__ bbv, unsigned short* __restrict__ Ob)
{
  __shared__ __align__(16) unsigned short Qa[32*40];
  __shared__ __align__(16) unsigned short Kl[256*40];
  __shared__ __align__(16) unsigned short Vt[32*264];
  __shared__ __align__(16) unsigned short Pl[32*264];
  __shared__ float srowm[4][16], srows[4][16], sinv[32];

  const int tid = threadIdx.x;
  const int ic = blockIdx.x & 7, bh = blockIdx.x >> 3;
  const int i0 = ic * 32;
  const int w = tid>>6, l = tid&63, lrow = l&15, quad = l>>4;

  if (tid < 128){
    int r = tid>>2, cseg = tid&3;
    *(uint4*)(Qa + r*40 + cseg*8) = ((const uint4*)(Qb + (size_t)(bh*256+i0)*32))[tid];
  }
#pragma unroll
  for (int s=0;s<4;s++){
    int f = tid + s*256; int r = f>>2, cseg = f&3;
    *(uint4*)(Kl + r*40 + cseg*8) = ((const uint4*)(Kb + (size_t)bh*8192))[f];
  }
#pragma unroll
  for (int s=0;s<4;s++){
    int f = tid + s*256; int r = f>>5, c8 = f&31;
    *(uint4*)(Vt + r*264 + c8*8) = ((const uint4*)(VTb + (size_t)bh*8192))[f];
  }
  __syncthreads();

  const int rt = w & 1, cs = (w>>1)*8;
  const float bbh = bbv[bh & 7];
  floatx4 sc[8];
  {
    shortx8 aq = *(const shortx8*)(Qa + (rt*16+lrow)*40 + quad*8);
    floatx4 z = (floatx4){0.f,0.f,0.f,0.f};
#pragma unroll
    for (int t=0;t<8;t++){
      shortx8 bk = *(const shortx8*)(Kl + ((cs+t)*16+lrow)*40 + quad*8);
      sc[t] = __builtin_amdgcn_mfma_f32_16x16x32_bf16(aq, bk, z, 0, 0, 0);
    }
  }
  const float scale = 0.17677669529663687f;
  float mx[4] = {-1e30f,-1e30f,-1e30f,-1e30f};
#pragma unroll
  for (int t=0;t<8;t++){
#pragma unroll
    for (int reg=0;reg<4;reg++){
      size_t bidx = ((size_t)(bh*256 + i0 + rt*16 + quad*4 + reg))*256 + (cs+t)*16 + lrow;
      float v = sc[t][reg]*scale + bias[bidx] + bbh;
      sc[t][reg] = v;
      mx[reg] = fmaxf(mx[reg], v);
    }
  }
#pragma unroll
  for (int m=1;m<16;m<<=1){
#pragma unroll
    for (int reg=0;reg<4;reg++) mx[reg] = fmaxf(mx[reg], __shfl_xor(mx[reg], m));
  }
  if (lrow == 0){
#pragma unroll
    for (int reg=0;reg<4;reg++) srowm[w][quad*4+reg] = mx[reg];
  }
  __syncthreads();
  float sum[4] = {0.f,0.f,0.f,0.f};
#pragma unroll
  for (int reg=0;reg<4;reg++){
    float gm = fmaxf(srowm[w][quad*4+reg], srowm[w^2][quad*4+reg]);
#pragma unroll
    for (int t=0;t<8;t++){
      float p = __expf(sc[t][reg] - gm);
      sc[t][reg] = p; sum[reg] += p;
    }
  }
#pragma unroll
  for (int m=1;m<16;m<<=1){
#pragma unroll
    for (int reg=0;reg<4;reg++) sum[reg] += __shfl_xor(sum[reg], m);
  }
  if (lrow == 0){
#pragma unroll
    for (int reg=0;reg<4;reg++) srows[w][quad*4+reg] = sum[reg];
  }
#pragma unroll
  for (int t=0;t<8;t++){
#pragma unroll
    for (int reg=0;reg<4;reg++)
      Pl[(rt*16+quad*4+reg)*264 + (cs+t)*16 + lrow] = f2bf(sc[t][reg]);
  }
  __syncthreads();
  if (lrow == 0 && w < 2){
#pragma unroll
    for (int reg=0;reg<4;reg++){
      int row = rt*16 + quad*4 + reg;
      sinv[row] = 1.f/(srows[w][quad*4+reg] + srows[w^2][quad*4+reg]);
    }
  }
  __syncthreads();
  // phase 2: P @ V^T
  const int rt2 = w & 1, ctd = w >> 1;
  floatx4 oc = (floatx4){0.f,0.f,0.f,0.f};
#pragma unroll
  for (int kc=0;kc<8;kc++){
    shortx8 ap = *(const shortx8*)(Pl + (rt2*16+lrow)*264 + kc*32 + quad*8);
    shortx8 bv = *(const shortx8*)(Vt + (ctd*16+lrow)*264 + kc*32 + quad*8);
    oc = __builtin_amdgcn_mfma_f32_16x16x32_bf16(ap, bv, oc, 0, 0, 0);
  }
  const int bq = bh >> 3, hh = bh & 7;
#pragma unroll
  for (int reg=0;reg<4;reg++){
    int row = rt2*16 + quad*4 + reg;
    int d = ctd*16 + lrow;
    Ob[((size_t)(bq*256 + i0 + row))*256 + hh*32 + d] = f2bf(oc[reg]*sinv[row]);
  }
}

// ---------------- K4: fused back: oproj+res+LN2+FFN1+GELU+FFN2+res ----------------
__global__ __launch_bounds__(256) void k_back(
  const unsigned short* __restrict__ Ob, const unsigned short* __restrict__ WoT,
  const float* __restrict__ bo, const float* __restrict__ h,
  const float* __restrict__ g2, const float* __restrict__ b2l,
  const unsigned short* __restrict__ W1T, const float* __restrict__ b1f,
  const unsigned short* __restrict__ W2T, const float* __restrict__ b2f,
  float* __restrict__ out)
{
  __shared__ __align__(16) unsigned short Os[16*264];
  __shared__ float h1s[16*264];
  __shared__ __align__(16) unsigned short ys[16*264];
  __shared__ __align__(16) unsigned short Gs[16*1032];
  __shared__ float red1[16][16], red2[16][16];
  __shared__ float rmean[16], rinv[16];

  const int tid = threadIdx.x;
  const int row0 = blockIdx.x * 16;
  const int w = tid>>6, l = tid&63, lrow = l&15, quad = l>>4;

#pragma unroll
  for (int s=0;s<2;s++){
    int f = tid + s*256; int r = f>>5, c8 = f&31;
    *(uint4*)(Os + r*264 + c8*8) = ((const uint4*)(Ob + (size_t)row0*256))[f];
  }
  __syncthreads();
  // GEMM1: o @ WoT + bo + h -> h1s
  {
    floatx4 a4[4];
#pragma unroll
    for (int t=0;t<4;t++) a4[t] = (floatx4){0.f,0.f,0.f,0.f};
    for (int c=0;c<8;c++){
      shortx8 af = *(const shortx8*)(Os + lrow*264 + c*32 + quad*8);
#pragma unroll
      for (int t=0;t<4;t++){
        int n = (w*4+t)*16 + lrow;
        shortx8 bf = *(const shortx8*)(WoT + (size_t)n*256 + c*32 + quad*8);
        a4[t] = __builtin_amdgcn_mfma_f32_16x16x32_bf16(af, bf, a4[t], 0, 0, 0);
      }
    }
#pragma unroll
    for (int t=0;t<4;t++){
#pragma unroll
      for (int reg=0;reg<4;reg++){
        int row = quad*4+reg, col = (w*4+t)*16+lrow;
        h1s[row*264+col] = a4[t][reg] + bo[col] + h[(size_t)(row0+row)*256 + col];
      }
    }
  }
  __syncthreads();
  // LN2 -> ys (bf16)
  {
    int row = tid>>4, l16 = tid&15;
    float sm=0.f, sq=0.f;
#pragma unroll
    for (int j=0;j<16;j++){ float v = h1s[row*264 + l16*16 + j]; sm+=v; sq+=v*v; }
    red1[row][l16]=sm; red2[row][l16]=sq;
    __syncthreads();
    if (l16==0){
      float s0=0.f,q0=0.f;
#pragma unroll
      for (int k=0;k<16;k++){ s0+=red1[row][k]; q0+=red2[row][k]; }
      float m = s0*(1.f/256.f);
      rmean[row]=m; rinv[row]=rsqrtf(q0*(1.f/256.f)-m*m+EPS);
    }
    __syncthreads();
    float m = rmean[row], iv = rinv[row];
#pragma unroll
    for (int j=0;j<16;j++){ int col = l16*16+j;
      ys[row*264+col] = f2bf((h1s[row*264+col]-m)*iv*g2[col] + b2l[col]); }
  }
  __syncthreads();
  // GEMM2: y @ W1T + b1 -> GELU -> Gs
  {
    floatx4 a4[16];
#pragma unroll
    for (int t=0;t<16;t++) a4[t] = (floatx4){0.f,0.f,0.f,0.f};
    for (int c=0;c<8;c++){
      shortx8 af = *(const shortx8*)(ys + lrow*264 + c*32 + quad*8);
#pragma unroll
      for (int t=0;t<16;t++){
        int n = (w*16+t)*16 + lrow;
        shortx8 bf = *(const shortx8*)(W1T + (size_t)n*256 + c*32 + quad*8);
        a4[t] = __builtin_amdgcn_mfma_f32_16x16x32_bf16(af, bf, a4[t], 0, 0, 0);
      }
    }
#pragma unroll
    for (int t=0;t<16;t++){
#pragma unroll
      for (int reg=0;reg<4;reg++){
        int row = quad*4+reg, col = (w*16+t)*16+lrow;
        float v = a4[t][reg] + b1f[col];
        float ge = 0.5f*v*(1.f + erff(v*0.70710678118654752f));
        Gs[row*1032+col] = f2bf(ge);
      }
    }
  }
  __syncthreads();
  // GEMM3: G @ W2T + b2 + h1 -> out
  {
    floatx4 a4[4];
#pragma unroll
    for (int t=0;t<4;t++) a4[t] = (floatx4){0.f,0.f,0.f,0.f};
    for (int c=0;c<32;c++){
      shortx8 af = *(const shortx8*)(Gs + lrow*1032 + c*32 + quad*8);
#pragma unroll
      for (int t=0;t<4;t++){
        int n = (w*4+t)*16 + lrow;
        shortx8 bf = *(const shortx8*)(W2T + (size_t)n*1024 + c*32 + quad*8);
        a4[t] = __builtin_amdgcn_mfma_f32_16x16x32_bf16(af, bf, a4[t], 0, 0, 0);
      }
    }
#pragma unroll
    for (int t=0;t<4;t++){
#pragma unroll
      for (int reg=0;reg<4;reg++){
        int row = quad*4+reg, col = (w*4+t)*16+lrow;
        out[(size_t)(row0+row)*256+col] = h1s[row*264+col] + a4[t][reg] + b2f[col];
      }
    }
  }
}

extern "C" void kernel_launch(void* const* d_in, const int* in_sizes, int n_in,
                              void* d_out, int out_size, void* d_ws, size_t ws_size,
                              hipStream_t stream)
{
  (void)in_sizes; (void)n_in; (void)out_size; (void)ws_size;
  const float* h    = (const float*)d_in[0];
  const float* e    = (const float*)d_in[1];
  const float* We   = (const float*)d_in[2];
  const float* be   = (const float*)d_in[3];
  const float* Ws   = (const float*)d_in[4];
  const float* bs   = (const float*)d_in[5];
  const float* Wd   = (const float*)d_in[6];
  const float* bd   = (const float*)d_in[7];
  const float* Wb   = (const float*)d_in[8];
  const float* bb   = (const float*)d_in[9];
  const float* g1   = (const float*)d_in[10];
  const float* b1l  = (const float*)d_in[11];
  const float* Wqkv = (const float*)d_in[12];
  const float* bqkv = (const float*)d_in[13];
  const float* Wo   = (const float*)d_in[14];
  const float* bo   = (const float*)d_in[15];
  const float* g2   = (const float*)d_in[16];
  const float* b2l  = (const float*)d_in[17];
  const float* W1   = (const float*)d_in[18];
  const float* b1f  = (const float*)d_in[19];
  const float* W2   = (const float*)d_in[20];
  const float* b2f  = (const float*)d_in[21];

  float* out  = (float*)d_out;
  float* h2_o = out;               // [B,N,D]
  float* e_o  = out + 262144;      // [B,N,N,D]

  float* wsf = (float*)d_ws;
  unsigned short* ush = (unsigned short*)d_ws;
  unsigned short* WeT   = ush;                 // 65536
  unsigned short* WsT   = ush + 65536;         // 65536
  unsigned short* WdT   = ush + 131072;        // 65536
  unsigned short* WqkvT = ush + 196608;        // 196608
  unsigned short* WoT   = ush + 393216;        // 65536
  unsigned short* W1T   = ush + 458752;        // 262144
  unsigned short* W2T   = ush + 720896;        // 262144
  unsigned short* WbT16 = ush + 983040;        // 4096  -> total 987136 ush = 493568 f
  float* S_   = wsf + 493568;                  // 262144
  float* T_   = wsf + 755712;                  // 262144
  float* bias = wsf + 1017856;                 // 2097152 -> 3115008
  unsigned short* Qb  = (unsigned short*)(wsf + 3115008); // 262144 ush
  unsigned short* Kb  = (unsigned short*)(wsf + 3246080);
  unsigned short* VTb = (unsigned short*)(wsf + 3377152);
  unsigned short* Ob  = (unsigned short*)(wsf + 3508224); // end 3639296 f (~14.6 MB)

  k_prep <<<dim3(241),  dim3(256), 0, stream>>>(We,Ws,Wd,Wqkv,Wo,W1,W2,Wb,
                                                WeT,WsT,WdT,WqkvT,WoT,W1T,W2T,WbT16);
  k_front<<<dim3(320),  dim3(256), 0, stream>>>(h, g1,b1l, bs,be,bd, bqkv,
                                                WsT,WdT,WqkvT, S_,T_, Qb,Kb,VTb);
  k_edge <<<dim3(4096), dim3(256), 0, stream>>>(e, WeT, S_, T_, WbT16, e_o, bias);
  k_attn <<<dim3(256),  dim3(256), 0, stream>>>(Qb, Kb, VTb, bias, bb, Ob);
  k_back <<<dim3(64),   dim3(256), 0, stream>>>(Ob, WoT, bo, h, g2,b2l,
                                                W1T,b1f, W2T,b2f, h2_o);
}

// Round 2
// 735.453 us; speedup vs baseline: 1.0652x; 1.0652x over previous
//
#include <hip/hip_runtime.h>
#include <math.h>

#define EPS 1e-5f

typedef __attribute__((ext_vector_type(4))) float floatx4;
typedef __attribute__((ext_vector_type(8))) short shortx8;

__device__ __forceinline__ unsigned short f2bf(float f){
  union { float f; unsigned u; } v; v.f = f;
  unsigned r = v.u + 0x7FFFu + ((v.u >> 16) & 1u);
  return (unsigned short)(r >> 16);
}
__device__ __forceinline__ float bf2f(unsigned short s){
  union { unsigned u; float f; } v; v.u = ((unsigned)s) << 16;
  return v.f;
}

// ---------------- K0: all weights -> bf16 transposed [n][k] ----------------
__global__ __launch_bounds__(256) void k_prep(
    const float* __restrict__ We, const float* __restrict__ Ws, const float* __restrict__ Wd,
    const float* __restrict__ Wqkv, const float* __restrict__ Wo, const float* __restrict__ W1,
    const float* __restrict__ W2, const float* __restrict__ Wb,
    unsigned short* __restrict__ WeT, unsigned short* __restrict__ WsT,
    unsigned short* __restrict__ WdT, unsigned short* __restrict__ WqkvT,
    unsigned short* __restrict__ WoT, unsigned short* __restrict__ W1T,
    unsigned short* __restrict__ W2T, unsigned short* __restrict__ WbT16)
{
  const int blk = blockIdx.x, tid = threadIdx.x;
  if (blk == 240){
#pragma unroll
    for (int hh=0; hh<8; hh++) WbT16[hh*256+tid] = f2bf(Wb[tid*8+hh]);
#pragma unroll
    for (int hh=8; hh<16; hh++) WbT16[hh*256+tid] = 0;
    return;
  }
  const float* src; unsigned short* dst; int K, N, t;
  if (blk < 16)      { src=We;   dst=WeT;   K=256;  N=256;  t=blk; }
  else if (blk < 32) { src=Ws;   dst=WsT;   K=256;  N=256;  t=blk-16; }
  else if (blk < 48) { src=Wd;   dst=WdT;   K=256;  N=256;  t=blk-32; }
  else if (blk < 96) { src=Wqkv; dst=WqkvT; K=256;  N=768;  t=blk-48; }
  else if (blk < 112){ src=Wo;   dst=WoT;   K=256;  N=256;  t=blk-96; }
  else if (blk < 176){ src=W1;   dst=W1T;   K=256;  N=1024; t=blk-112; }
  else               { src=W2;   dst=W2T;   K=1024; N=256;  t=blk-176; }
  const int tpr = N >> 6;
  const int k0 = (t / tpr) << 6, n0 = (t % tpr) << 6;
  __shared__ float tile[64][65];
#pragma unroll
  for (int s=0;s<16;s++){ int f=tid+(s<<8); int r=f>>6, c=f&63;
    tile[r][c] = src[(size_t)(k0+r)*N + n0 + c]; }
  __syncthreads();
#pragma unroll
  for (int s=0;s<16;s++){ int f=tid+(s<<8); int r=f>>6, c=f&63;
    dst[(size_t)(n0+r)*K + k0 + c] = f2bf(tile[c][r]); }
}

// ---------------- K1: fused front: S,T,Q,K,V (per 16-row block, per col-chunk) ----
__global__ __launch_bounds__(256) void k_front(
  const float* __restrict__ h, const float* __restrict__ g1, const float* __restrict__ b1l,
  const float* __restrict__ bs, const float* __restrict__ be, const float* __restrict__ bd,
  const float* __restrict__ bqkv,
  const unsigned short* __restrict__ WsT, const unsigned short* __restrict__ WdT,
  const unsigned short* __restrict__ WqkvT,
  float* __restrict__ S, float* __restrict__ T,
  unsigned short* __restrict__ Qb, unsigned short* __restrict__ Kb,
  unsigned short* __restrict__ VTb)
{
  __shared__ float hs[16][256];
  __shared__ __align__(16) unsigned short xa[16*264];
  __shared__ float red1[16][16], red2[16][16];
  __shared__ float rmean[16], rinv[16];
  const int tid = threadIdx.x;
  const int rb = blockIdx.x & 63;
  const int chunk = blockIdx.x >> 6;
  const int row0 = rb * 16;
  const int b = row0 >> 8;
  const int w = tid>>6, l = tid&63, lrow = l&15, quad = l>>4;

#pragma unroll
  for (int s=0;s<4;s++){
    int f = tid + s*256; int r = f>>6, c4 = f&63;
    float4 v = ((const float4*)(h + (size_t)row0*256))[f];
    *(float4*)(&hs[r][c4*4]) = v;
  }
  __syncthreads();
  {
    int row = tid>>4, l16 = tid&15;
    if (chunk >= 2){
      float sm=0.f, sq=0.f;
#pragma unroll
      for (int j=0;j<16;j++){ float v=hs[row][l16*16+j]; sm+=v; sq+=v*v; }
      red1[row][l16]=sm; red2[row][l16]=sq;
      __syncthreads();
      if (l16==0){
        float s0=0.f,q0=0.f;
#pragma unroll
        for(int k=0;k<16;k++){ s0+=red1[row][k]; q0+=red2[row][k]; }
        float m=s0*(1.f/256.f);
        rmean[row]=m; rinv[row]=rsqrtf(q0*(1.f/256.f)-m*m+EPS);
      }
      __syncthreads();
      float m=rmean[row], iv=rinv[row];
#pragma unroll
      for (int j=0;j<16;j++){ int col=l16*16+j;
        xa[row*264+col] = f2bf((hs[row][col]-m)*iv*g1[col] + b1l[col]); }
    } else {
#pragma unroll
      for (int j=0;j<16;j++){ int col=l16*16+j; xa[row*264+col] = f2bf(hs[row][col]); }
    }
  }
  __syncthreads();
  const unsigned short* Wt;
  if (chunk==0) Wt = WsT; else if (chunk==1) Wt = WdT;
  else Wt = WqkvT + (size_t)(chunk-2)*256*256;
  floatx4 a4[4];
#pragma unroll
  for (int t=0;t<4;t++) a4[t] = (floatx4){0.f,0.f,0.f,0.f};
  for (int c=0;c<8;c++){
    shortx8 af = *(const shortx8*)(xa + lrow*264 + c*32 + quad*8);
#pragma unroll
    for (int t=0;t<4;t++){
      int n = (w*4+t)*16 + lrow;
      shortx8 bf = *(const shortx8*)(Wt + (size_t)n*256 + c*32 + quad*8);
      a4[t] = __builtin_amdgcn_mfma_f32_16x16x32_bf16(af, bf, a4[t], 0, 0, 0);
    }
  }
#pragma unroll
  for (int t=0;t<4;t++){
    int ct = w*4+t;
#pragma unroll
    for (int reg=0;reg<4;reg++){
      int row = quad*4+reg, col = ct*16+lrow;
      float v = a4[t][reg];
      if (chunk==0) S[(size_t)(row0+row)*256+col] = v + bs[col] + be[col];
      else if (chunk==1) T[(size_t)(row0+row)*256+col] = v + bd[col];
      else if (chunk==2){ float q = v + bqkv[col]; int hh=col>>5, d=col&31;
        Qb[((size_t)(b*8+hh)*256 + (row0&255)+row)*32 + d] = f2bf(q); }
      else if (chunk==3){ float q = v + bqkv[256+col]; int hh=col>>5, d=col&31;
        Kb[((size_t)(b*8+hh)*256 + (row0&255)+row)*32 + d] = f2bf(q); }
      else { float q = v + bqkv[512+col]; int hh=col>>5, d=col&31;
        VTb[((size_t)(b*8+hh)*32 + d)*256 + (row0&255)+row] = f2bf(q); }
    }
  }
}

// ---------------- K2: e_new + fused bias — LDS-staged, BK=64, operand-swapped ----
// Wave w owns d-quarter [w*64, w*64+64) x all 64 j of the block's tile.
// A-operand = WeT fragment (m=d), B-operand = e fragment (n=j): each thread's
// acc quad holds 4 CONSECUTIVE d for fixed j -> float4 epilogue, packed En stores.
// Staging: As[64j][72] bf16(e), Bs[256d][72] WeT chunk; register prefetch of the
// next chunk is issued before each MFMA phase. 9 barriers total (v1 had 17).
// En (union with As/Bs head) feeds the fused bias GEMM after one barrier.
__global__ __launch_bounds__(256, 3) void k_edge(
    const float* __restrict__ e, const unsigned short* __restrict__ WeT,
    const float* __restrict__ S, const float* __restrict__ T,
    const unsigned short* __restrict__ WbTg,
    float* __restrict__ eo, float* __restrict__ bias)
{
  __shared__ __align__(16) unsigned short smem[23040]; // As(64x72)+Bs(256x72) | En(64x264)
  __shared__ float sbuf[256];
  unsigned short* As = smem;           // stride 72
  unsigned short* Bs = smem + 4608;    // stride 72
  unsigned short* En = smem;           // stride 264 (after main loop)

  const int tid = threadIdx.x;
  const int blk = blockIdx.x;
  const int jt = blk & 3;
  const int i  = (blk >> 2) & 255;
  const int b  = blk >> 10;
  const int j0 = jt * 64;
  const int w = tid >> 6, l = tid & 63;
  const int lrow = l & 15, quad = l >> 4;

  sbuf[tid] = S[((b << 8) + i) * 256 + tid];

  const float* eBase = e + ((size_t)((b*256 + i)*256 + j0)) * 256;
  // staging maps (f = tid + s*256):
  //   e:   rE = f>>4 (0..63), cE = (f&15)*4   -> 256B contiguous per row
  //   WeT: nW = f>>3 (0..255), sW = (f&7)*8   -> 128B contiguous per row
  const int rE = tid >> 4;
  const int cE = (tid & 15) * 4;
  const int nW = tid >> 3;
  const int sW = (tid & 7) * 8;

  float4 pe[4]; uint4 pw[8];
#pragma unroll
  for (int s=0;s<4;s++) pe[s] = *(const float4*)(eBase + (size_t)(rE + s*16)*256 + cE);
#pragma unroll
  for (int s=0;s<8;s++) pw[s] = *(const uint4*)(WeT + (size_t)(nW + s*32)*256 + sW);
#pragma unroll
  for (int s=0;s<4;s++){
    uint2 pk;
    pk.x = (unsigned)f2bf(pe[s].x) | ((unsigned)f2bf(pe[s].y) << 16);
    pk.y = (unsigned)f2bf(pe[s].z) | ((unsigned)f2bf(pe[s].w) << 16);
    *(uint2*)(As + (rE + s*16)*72 + cE) = pk;
  }
#pragma unroll
  for (int s=0;s<8;s++) *(uint4*)(Bs + (nW + s*32)*72 + sW) = pw[s];
  __syncthreads();

  floatx4 acc[4][4];
#pragma unroll
  for (int jg=0;jg<4;jg++)
#pragma unroll
    for (int t=0;t<4;t++) acc[jg][t] = (floatx4){0.f,0.f,0.f,0.f};

  for (int c = 0; c < 4; ++c){
    if (c < 3){
      const int k0 = (c+1)*64;
#pragma unroll
      for (int s=0;s<4;s++) pe[s] = *(const float4*)(eBase + (size_t)(rE + s*16)*256 + k0 + cE);
#pragma unroll
      for (int s=0;s<8;s++) pw[s] = *(const uint4*)(WeT + (size_t)(nW + s*32)*256 + k0 + sW);
    }
#pragma unroll
    for (int ks=0;ks<2;ks++){
      shortx8 ef0 = *(const shortx8*)(As + ( 0 + lrow)*72 + ks*32 + quad*8);
      shortx8 ef1 = *(const shortx8*)(As + (16 + lrow)*72 + ks*32 + quad*8);
      shortx8 ef2 = *(const shortx8*)(As + (32 + lrow)*72 + ks*32 + quad*8);
      shortx8 ef3 = *(const shortx8*)(As + (48 + lrow)*72 + ks*32 + quad*8);
#pragma unroll
      for (int t=0;t<4;t++){
        shortx8 wf = *(const shortx8*)(Bs + ((w*4+t)*16 + lrow)*72 + ks*32 + quad*8);
        acc[0][t] = __builtin_amdgcn_mfma_f32_16x16x32_bf16(wf, ef0, acc[0][t], 0, 0, 0);
        acc[1][t] = __builtin_amdgcn_mfma_f32_16x16x32_bf16(wf, ef1, acc[1][t], 0, 0, 0);
        acc[2][t] = __builtin_amdgcn_mfma_f32_16x16x32_bf16(wf, ef2, acc[2][t], 0, 0, 0);
        acc[3][t] = __builtin_amdgcn_mfma_f32_16x16x32_bf16(wf, ef3, acc[3][t], 0, 0, 0);
      }
    }
    __syncthreads();
    if (c < 3){
#pragma unroll
      for (int s=0;s<4;s++){
        uint2 pk;
        pk.x = (unsigned)f2bf(pe[s].x) | ((unsigned)f2bf(pe[s].y) << 16);
        pk.y = (unsigned)f2bf(pe[s].z) | ((unsigned)f2bf(pe[s].w) << 16);
        *(uint2*)(As + (rE + s*16)*72 + cE) = pk;
      }
#pragma unroll
      for (int s=0;s<8;s++) *(uint4*)(Bs + (nW + s*32)*72 + sW) = pw[s];
      __syncthreads();
    }
  }

  // epilogue: v = acc + S[d] + T[j][d], relu; float4 -> e_o direct (fp32 exact),
  // packed uint2 bf16 -> En for the fused bias GEMM.
  const float* Tb = T + (size_t)(b*256 + j0) * 256;
  float* eop = eo + ((size_t)((b*256 + i)*256 + j0)) * 256;
#pragma unroll
  for (int jg=0;jg<4;jg++){
    const int jl = jg*16 + lrow;
    const float* Trow = Tb + (size_t)jl*256;
    float* erow = eop + (size_t)jl*256;
#pragma unroll
    for (int t=0;t<4;t++){
      const int d0 = (w*4+t)*16 + quad*4;
      float4 sv = *(const float4*)(&sbuf[d0]);
      float4 tv = *(const float4*)(Trow + d0);
      float v0 = fmaxf(acc[jg][t][0] + sv.x + tv.x, 0.f);
      float v1 = fmaxf(acc[jg][t][1] + sv.y + tv.y, 0.f);
      float v2 = fmaxf(acc[jg][t][2] + sv.z + tv.z, 0.f);
      float v3 = fmaxf(acc[jg][t][3] + sv.w + tv.w, 0.f);
      float4 ov; ov.x = v0; ov.y = v1; ov.z = v2; ov.w = v3;
      *(float4*)(erow + d0) = ov;
      uint2 pk;
      pk.x = (unsigned)f2bf(v0) | ((unsigned)f2bf(v1) << 16);
      pk.y = (unsigned)f2bf(v2) | ((unsigned)f2bf(v3) << 16);
      *(uint2*)(En + jl*264 + d0) = pk;
    }
  }
  __syncthreads();

  // fused bias: (64 j x 256 d) @ WbT -> [h][j]
  floatx4 accb = (floatx4){0.f,0.f,0.f,0.f};
#pragma unroll
  for (int c8 = 0; c8 < 8; c8++){
    int k0 = c8*32;
    shortx8 af = *(const shortx8*)(En + (w*16 + lrow)*264 + k0 + quad*8);
    shortx8 bfrag = *(const shortx8*)(WbTg + lrow*256 + k0 + quad*8);
    accb = __builtin_amdgcn_mfma_f32_16x16x32_bf16(af, bfrag, accb, 0, 0, 0);
  }
  if (lrow < 8){
    float* bp = bias + ((size_t)((b*8 + lrow)*256 + i)) * 256;
    int jb = j0 + w*16 + quad*4;
#pragma unroll
    for (int r = 0; r < 4; r++) bp[jb + r] = accb[r];
  }
}

// ---------------- K3: attention, one block per (bh, 32-row i-chunk) ----------------
__global__ __launch_bounds__(256) void k_attn(
  const unsigned short* __restrict__ Qb, const unsigned short* __restrict__ Kb,
  const unsigned short* __restrict__ VTb, const float* __restrict__ bias,
  const float* __restrict__ bbv, unsigned short* __restrict__ Ob)
{
  __shared__ __align__(16) unsigned short Qa[32*40];
  __shared__ __align__(16) unsigned short Kl[256*40];
  __shared__ __align__(16) unsigned short Vt[32*264];
  __shared__ __align__(16) unsigned short Pl[32*264];
  __shared__ float srowm[4][16], srows[4][16], sinv[32];

  const int tid = threadIdx.x;
  const int ic = blockIdx.x & 7, bh = blockIdx.x >> 3;
  const int i0 = ic * 32;
  const int w = tid>>6, l = tid&63, lrow = l&15, quad = l>>4;

  if (tid < 128){
    int r = tid>>2, cseg = tid&3;
    *(uint4*)(Qa + r*40 + cseg*8) = ((const uint4*)(Qb + (size_t)(bh*256+i0)*32))[tid];
  }
#pragma unroll
  for (int s=0;s<4;s++){
    int f = tid + s*256; int r = f>>2, cseg = f&3;
    *(uint4*)(Kl + r*40 + cseg*8) = ((const uint4*)(Kb + (size_t)bh*8192))[f];
  }
#pragma unroll
  for (int s=0;s<4;s++){
    int f = tid + s*256; int r = f>>5, c8 = f&31;
    *(uint4*)(Vt + r*264 + c8*8) = ((const uint4*)(VTb + (size_t)bh*8192))[f];
  }
  __syncthreads();

  const int rt = w & 1, cs = (w>>1)*8;
  const float bbh = bbv[bh & 7];
  floatx4 sc[8];
  {
    shortx8 aq = *(const shortx8*)(Qa + (rt*16+lrow)*40 + quad*8);
    floatx4 z = (floatx4){0.f,0.f,0.f,0.f};
#pragma unroll
    for (int t=0;t<8;t++){
      shortx8 bk = *(const shortx8*)(Kl + ((cs+t)*16+lrow)*40 + quad*8);
      sc[t] = __builtin_amdgcn_mfma_f32_16x16x32_bf16(aq, bk, z, 0, 0, 0);
    }
  }
  const float scale = 0.17677669529663687f;
  float mx[4] = {-1e30f,-1e30f,-1e30f,-1e30f};
#pragma unroll
  for (int t=0;t<8;t++){
#pragma unroll
    for (int reg=0;reg<4;reg++){
      size_t bidx = ((size_t)(bh*256 + i0 + rt*16 + quad*4 + reg))*256 + (cs+t)*16 + lrow;
      float v = sc[t][reg]*scale + bias[bidx] + bbh;
      sc[t][reg] = v;
      mx[reg] = fmaxf(mx[reg], v);
    }
  }
#pragma unroll
  for (int m=1;m<16;m<<=1){
#pragma unroll
    for (int reg=0;reg<4;reg++) mx[reg] = fmaxf(mx[reg], __shfl_xor(mx[reg], m));
  }
  if (lrow == 0){
#pragma unroll
    for (int reg=0;reg<4;reg++) srowm[w][quad*4+reg] = mx[reg];
  }
  __syncthreads();
  float sum[4] = {0.f,0.f,0.f,0.f};
#pragma unroll
  for (int reg=0;reg<4;reg++){
    float gm = fmaxf(srowm[w][quad*4+reg], srowm[w^2][quad*4+reg]);
#pragma unroll
    for (int t=0;t<8;t++){
      float p = __expf(sc[t][reg] - gm);
      sc[t][reg] = p; sum[reg] += p;
    }
  }
#pragma unroll
  for (int m=1;m<16;m<<=1){
#pragma unroll
    for (int reg=0;reg<4;reg++) sum[reg] += __shfl_xor(sum[reg], m);
  }
  if (lrow == 0){
#pragma unroll
    for (int reg=0;reg<4;reg++) srows[w][quad*4+reg] = sum[reg];
  }
#pragma unroll
  for (int t=0;t<8;t++){
#pragma unroll
    for (int reg=0;reg<4;reg++)
      Pl[(rt*16+quad*4+reg)*264 + (cs+t)*16 + lrow] = f2bf(sc[t][reg]);
  }
  __syncthreads();
  if (lrow == 0 && w < 2){
#pragma unroll
    for (int reg=0;reg<4;reg++){
      int row = rt*16 + quad*4 + reg;
      sinv[row] = 1.f/(srows[w][quad*4+reg] + srows[w^2][quad*4+reg]);
    }
  }
  __syncthreads();
  // phase 2: P @ V^T
  const int rt2 = w & 1, ctd = w >> 1;
  floatx4 oc = (floatx4){0.f,0.f,0.f,0.f};
#pragma unroll
  for (int kc=0;kc<8;kc++){
    shortx8 ap = *(const shortx8*)(Pl + (rt2*16+lrow)*264 + kc*32 + quad*8);
    shortx8 bv = *(const shortx8*)(Vt + (ctd*16+lrow)*264 + kc*32 + quad*8);
    oc = __builtin_amdgcn_mfma_f32_16x16x32_bf16(ap, bv, oc, 0, 0, 0);
  }
  const int bq = bh >> 3, hh = bh & 7;
#pragma unroll
  for (int reg=0;reg<4;reg++){
    int row = rt2*16 + quad*4 + reg;
    int d = ctd*16 + lrow;
    Ob[((size_t)(bq*256 + i0 + row))*256 + hh*32 + d] = f2bf(oc[reg]*sinv[row]);
  }
}

// ---------------- K4: fused back: oproj+res+LN2+FFN1+GELU+FFN2+res ----------------
__global__ __launch_bounds__(256) void k_back(
  const unsigned short* __restrict__ Ob, const unsigned short* __restrict__ WoT,
  const float* __restrict__ bo, const float* __restrict__ h,
  const float* __restrict__ g2, const float* __restrict__ b2l,
  const unsigned short* __restrict__ W1T, const float* __restrict__ b1f,
  const unsigned short* __restrict__ W2T, const float* __restrict__ b2f,
  float* __restrict__ out)
{
  __shared__ __align__(16) unsigned short Os[16*264];
  __shared__ float h1s[16*264];
  __shared__ __align__(16) unsigned short ys[16*264];
  __shared__ __align__(16) unsigned short Gs[16*1032];
  __shared__ float red1[16][16], red2[16][16];
  __shared__ float rmean[16], rinv[16];

  const int tid = threadIdx.x;
  const int row0 = blockIdx.x * 16;
  const int w = tid>>6, l = tid&63, lrow = l&15, quad = l>>4;

#pragma unroll
  for (int s=0;s<2;s++){
    int f = tid + s*256; int r = f>>5, c8 = f&31;
    *(uint4*)(Os + r*264 + c8*8) = ((const uint4*)(Ob + (size_t)row0*256))[f];
  }
  __syncthreads();
  // GEMM1: o @ WoT + bo + h -> h1s
  {
    floatx4 a4[4];
#pragma unroll
    for (int t=0;t<4;t++) a4[t] = (floatx4){0.f,0.f,0.f,0.f};
    for (int c=0;c<8;c++){
      shortx8 af = *(const shortx8*)(Os + lrow*264 + c*32 + quad*8);
#pragma unroll
      for (int t=0;t<4;t++){
        int n = (w*4+t)*16 + lrow;
        shortx8 bf = *(const shortx8*)(WoT + (size_t)n*256 + c*32 + quad*8);
        a4[t] = __builtin_amdgcn_mfma_f32_16x16x32_bf16(af, bf, a4[t], 0, 0, 0);
      }
    }
#pragma unroll
    for (int t=0;t<4;t++){
#pragma unroll
      for (int reg=0;reg<4;reg++){
        int row = quad*4+reg, col = (w*4+t)*16+lrow;
        h1s[row*264+col] = a4[t][reg] + bo[col] + h[(size_t)(row0+row)*256 + col];
      }
    }
  }
  __syncthreads();
  // LN2 -> ys (bf16)
  {
    int row = tid>>4, l16 = tid&15;
    float sm=0.f, sq=0.f;
#pragma unroll
    for (int j=0;j<16;j++){ float v = h1s[row*264 + l16*16 + j]; sm+=v; sq+=v*v; }
    red1[row][l16]=sm; red2[row][l16]=sq;
    __syncthreads();
    if (l16==0){
      float s0=0.f,q0=0.f;
#pragma unroll
      for (int k=0;k<16;k++){ s0+=red1[row][k]; q0+=red2[row][k]; }
      float m = s0*(1.f/256.f);
      rmean[row]=m; rinv[row]=rsqrtf(q0*(1.f/256.f)-m*m+EPS);
    }
    __syncthreads();
    float m = rmean[row], iv = rinv[row];
#pragma unroll
    for (int j=0;j<16;j++){ int col = l16*16+j;
      ys[row*264+col] = f2bf((h1s[row*264+col]-m)*iv*g2[col] + b2l[col]); }
  }
  __syncthreads();
  // GEMM2: y @ W1T + b1 -> GELU -> Gs
  {
    floatx4 a4[16];
#pragma unroll
    for (int t=0;t<16;t++) a4[t] = (floatx4){0.f,0.f,0.f,0.f};
    for (int c=0;c<8;c++){
      shortx8 af = *(const shortx8*)(ys + lrow*264 + c*32 + quad*8);
#pragma unroll
      for (int t=0;t<16;t++){
        int n = (w*16+t)*16 + lrow;
        shortx8 bf = *(const shortx8*)(W1T + (size_t)n*256 + c*32 + quad*8);
        a4[t] = __builtin_amdgcn_mfma_f32_16x16x32_bf16(af, bf, a4[t], 0, 0, 0);
      }
    }
#pragma unroll
    for (int t=0;t<16;t++){
#pragma unroll
      for (int reg=0;reg<4;reg++){
        int row = quad*4+reg, col = (w*16+t)*16+lrow;
        float v = a4[t][reg] + b1f[col];
        float ge = 0.5f*v*(1.f + erff(v*0.70710678118654752f));
        Gs[row*1032+col] = f2bf(ge);
      }
    }
  }
  __syncthreads();
  // GEMM3: G @ W2T + b2 + h1 -> out
  {
    floatx4 a4[4];
#pragma unroll
    for (int t=0;t<4;t++) a4[t] = (floatx4){0.f,0.f,0.f,0.f};
    for (int c=0;c<32;c++){
      shortx8 af = *(const shortx8*)(Gs + lrow*1032 + c*32 + quad*8);
#pragma unroll
      for (int t=0;t<4;t++){
        int n = (w*4+t)*16 + lrow;
        shortx8 bf = *(const shortx8*)(W2T + (size_t)n*1024 + c*32 + quad*8);
        a4[t] = __builtin_amdgcn_mfma_f32_16x16x32_bf16(af, bf, a4[t], 0, 0, 0);
      }
    }
#pragma unroll
    for (int t=0;t<4;t++){
#pragma unroll
      for (int reg=0;reg<4;reg++){
        int row = quad*4+reg, col = (w*4+t)*16+lrow;
        out[(size_t)(row0+row)*256+col] = h1s[row*264+col] + a4[t][reg] + b2f[col];
      }
    }
  }
}

extern "C" void kernel_launch(void* const* d_in, const int* in_sizes, int n_in,
                              void* d_out, int out_size, void* d_ws, size_t ws_size,
                              hipStream_t stream)
{
  (void)in_sizes; (void)n_in; (void)out_size; (void)ws_size;
  const float* h    = (const float*)d_in[0];
  const float* e    = (const float*)d_in[1];
  const float* We   = (const float*)d_in[2];
  const float* be   = (const float*)d_in[3];
  const float* Ws   = (const float*)d_in[4];
  const float* bs   = (const float*)d_in[5];
  const float* Wd   = (const float*)d_in[6];
  const float* bd   = (const float*)d_in[7];
  const float* Wb   = (const float*)d_in[8];
  const float* bb   = (const float*)d_in[9];
  const float* g1   = (const float*)d_in[10];
  const float* b1l  = (const float*)d_in[11];
  const float* Wqkv = (const float*)d_in[12];
  const float* bqkv = (const float*)d_in[13];
  const float* Wo   = (const float*)d_in[14];
  const float* bo   = (const float*)d_in[15];
  const float* g2   = (const float*)d_in[16];
  const float* b2l  = (const float*)d_in[17];
  const float* W1   = (const float*)d_in[18];
  const float* b1f  = (const float*)d_in[19];
  const float* W2   = (const float*)d_in[20];
  const float* b2f  = (const float*)d_in[21];

  float* out  = (float*)d_out;
  float* h2_o = out;               // [B,N,D]
  float* e_o  = out + 262144;      // [B,N,N,D]

  float* wsf = (float*)d_ws;
  unsigned short* ush = (unsigned short*)d_ws;
  unsigned short* WeT   = ush;                 // 65536
  unsigned short* WsT   = ush + 65536;         // 65536
  unsigned short* WdT   = ush + 131072;        // 65536
  unsigned short* WqkvT = ush + 196608;        // 196608
  unsigned short* WoT   = ush + 393216;        // 65536
  unsigned short* W1T   = ush + 458752;        // 262144
  unsigned short* W2T   = ush + 720896;        // 262144
  unsigned short* WbT16 = ush + 983040;        // 4096  -> total 987136 ush = 493568 f
  float* S_   = wsf + 493568;                  // 262144
  float* T_   = wsf + 755712;                  // 262144
  float* bias = wsf + 1017856;                 // 2097152 -> 3115008
  unsigned short* Qb  = (unsigned short*)(wsf + 3115008); // 262144 ush
  unsigned short* Kb  = (unsigned short*)(wsf + 3246080);
  unsigned short* VTb = (unsigned short*)(wsf + 3377152);
  unsigned short* Ob  = (unsigned short*)(wsf + 3508224); // end 3639296 f (~14.6 MB)

  k_prep <<<dim3(241),  dim3(256), 0, stream>>>(We,Ws,Wd,Wqkv,Wo,W1,W2,Wb,
                                                WeT,WsT,WdT,WqkvT,WoT,W1T,W2T,WbT16);
  k_front<<<dim3(320),  dim3(256), 0, stream>>>(h, g1,b1l, bs,be,bd, bqkv,
                                                WsT,WdT,WqkvT, S_,T_, Qb,Kb,VTb);
  k_edge <<<dim3(4096), dim3(256), 0, stream>>>(e, WeT, S_, T_, WbT16, e_o, bias);
  k_attn <<<dim3(256),  dim3(256), 0, stream>>>(Qb, Kb, VTb, bias, bb, Ob);
  k_back <<<dim3(64),   dim3(256), 0, stream>>>(Ob, WoT, bo, h, g2,b2l,
                                                W1T,b1f, W2T,b2f, h2_o);
}